// Round 2
// baseline (3328.701 us; speedup 1.0000x reference)
//
#include <hip/hip_runtime.h>
#include <hip/hip_bf16.h>
#include <cstdint>
#include <cstddef>

#define B_GRAPHS 2048
#define N_NODES  64
#define FIN      49
#define D_DIM    256
#define H_HEADS  8
#define DK_DIM   32
#define L_LAYERS 6
#define FC_DIM   128
#define ALPHA    0.2f

#define CHUNKS     2
#define G_CHUNK    (B_GRAPHS / CHUNKS)            // 1024 graphs per chunk
#define M_CHUNK    (G_CHUNK * N_NODES)            // 65536 rows per chunk

// ---------------------------------------------------------------------------
// Transpose weights: W_emb (256x49)->W_embT(49x256), gat_W (6,256,256)->K-major
// ---------------------------------------------------------------------------
__global__ void transpose_weights(const float* __restrict__ W_emb,
                                  const float* __restrict__ gat_W,
                                  float* __restrict__ W_embT,   // [49][256]
                                  float* __restrict__ gat_Wt)   // [6][256][256] (K-major)
{
    int idx = blockIdx.x * 256 + threadIdx.x;
    if (idx < FIN * D_DIM) {
        int k = idx / D_DIM, n = idx % D_DIM;
        W_embT[idx] = W_emb[n * FIN + k];
    }
    if (idx < L_LAYERS * D_DIM * D_DIM) {
        int l  = idx / (D_DIM * D_DIM);
        int kn = idx % (D_DIM * D_DIM);
        int k = kn / D_DIM, n = kn % D_DIM;
        gat_Wt[idx] = gat_W[(size_t)l * D_DIM * D_DIM + n * D_DIM + k];
    }
}

// ---------------------------------------------------------------------------
// C[M,256] = A[M,K] @ Bt[K,256] + bias.  BM=128, BN=256, BK=32.
// 256 threads, 8x16 register tile per thread. Grid = M/128.
// ---------------------------------------------------------------------------
__global__ __launch_bounds__(256, 2)
void gemm_bt(const float* __restrict__ A, int lda, int K,
             const float* __restrict__ Bt,
             const float* __restrict__ bias,
             float* __restrict__ C)
{
    __shared__ float a_lds[32 * 132];   // [k][m], padded
    __shared__ float b_lds[32 * 256];   // [k][n]

    const int tid = threadIdx.x;
    const int bm  = blockIdx.x * 128;
    const int tr  = tid >> 4;   // 0..15
    const int tc  = tid & 15;   // 0..15

    float acc[8][16];
#pragma unroll
    for (int i = 0; i < 8; i++)
#pragma unroll
        for (int j = 0; j < 16; j++) acc[i][j] = 0.f;

    for (int k0 = 0; k0 < K; k0 += 32) {
        // stage A tile (128 rows x 32 k), K-major into LDS
#pragma unroll
        for (int v = 0; v < 16; v++) {
            int idx = v * 256 + tid;
            int m = idx >> 5;
            int k = idx & 31;
            float val = (k0 + k < K) ? A[(size_t)(bm + m) * lda + k0 + k] : 0.f;
            a_lds[k * 132 + m] = val;
        }
        // stage B tile (32 k x 256 n)
#pragma unroll
        for (int v = 0; v < 8; v++) {
            int idx = v * 256 + tid;
            int k  = idx >> 6;
            int c4 = (idx & 63) << 2;
            float4 val;
            if (k0 + k < K) val = *(const float4*)&Bt[(size_t)(k0 + k) * 256 + c4];
            else            val = make_float4(0.f, 0.f, 0.f, 0.f);
            *(float4*)&b_lds[k * 256 + c4] = val;
        }
        __syncthreads();

#pragma unroll 4
        for (int k = 0; k < 32; k++) {
            float4 a0 = *(const float4*)&a_lds[k * 132 + tr * 4];
            float4 a1 = *(const float4*)&a_lds[k * 132 + 64 + tr * 4];
            float ar[8] = {a0.x, a0.y, a0.z, a0.w, a1.x, a1.y, a1.z, a1.w};
            float4 b0 = *(const float4*)&b_lds[k * 256 + tc * 4];
            float4 b1 = *(const float4*)&b_lds[k * 256 + tc * 4 + 64];
            float4 b2 = *(const float4*)&b_lds[k * 256 + tc * 4 + 128];
            float4 b3 = *(const float4*)&b_lds[k * 256 + tc * 4 + 192];
            float bc[16] = {b0.x, b0.y, b0.z, b0.w, b1.x, b1.y, b1.z, b1.w,
                            b2.x, b2.y, b2.z, b2.w, b3.x, b3.y, b3.z, b3.w};
#pragma unroll
            for (int r = 0; r < 8; r++)
#pragma unroll
                for (int c = 0; c < 16; c++)
                    acc[r][c] += ar[r] * bc[c];
        }
        __syncthreads();
    }

    // epilogue
#pragma unroll
    for (int q1 = 0; q1 < 2; q1++) {
#pragma unroll
        for (int a = 0; a < 4; a++) {
            int row = bm + q1 * 64 + tr * 4 + a;
#pragma unroll
            for (int q2 = 0; q2 < 4; q2++) {
                int col = q2 * 64 + tc * 4;
                float4 o;
                float b0 = bias ? bias[col + 0] : 0.f;
                float b1 = bias ? bias[col + 1] : 0.f;
                float b2 = bias ? bias[col + 2] : 0.f;
                float b3 = bias ? bias[col + 3] : 0.f;
                o.x = acc[q1 * 4 + a][q2 * 4 + 0] + b0;
                o.y = acc[q1 * 4 + a][q2 * 4 + 1] + b1;
                o.z = acc[q1 * 4 + a][q2 * 4 + 2] + b2;
                o.w = acc[q1 * 4 + a][q2 * 4 + 3] + b3;
                *(float4*)&C[(size_t)row * 256 + col] = o;
            }
        }
    }
}

// ---------------------------------------------------------------------------
// Fused GAT attention for one layer. One block per graph, 256 threads.
// hp = h @ W.T + b (precomputed). Updates h in place: h = elu(attn@hp + h).
// ---------------------------------------------------------------------------
__global__ __launch_bounds__(256, 2)
void gat_attn(const float* __restrict__ Amat,
              const float* __restrict__ hp,
              const float* __restrict__ a_vec,   // [8][64] for this layer
              float* __restrict__ h)
{
    __shared__ float lds_PT[2 * 64 * 64];   // [hh][j][i]  unnormalized numerators
    __shared__ float lds_V[64 * 64];        // [j][c]
    __shared__ float lds_es[64 * 8];
    __shared__ float lds_ed[64 * 8];
    __shared__ float lds_inv[2 * 64];
    __shared__ unsigned long long lds_Am[64];

    const int tid  = threadIdx.x;
    const int b    = blockIdx.x;
    const int lane = tid & 63;
    const int w    = tid >> 6;

    const float* Ab  = Amat + (size_t)b * 4096;
    const float* hpb = hp   + (size_t)b * 64 * 256;
    float*       hb  = h    + (size_t)b * 64 * 256;

    // A row bitmasks via wave ballot (row = v*4 + w, bit = j = lane)
    for (int v = 0; v < 16; v++) {
        float a = Ab[v * 256 + tid];
        unsigned long long m = __ballot(a > 0.f);
        if (lane == 0) lds_Am[v * 4 + w] = m;
    }

    // e_src / e_dst : 1024 dot-products of length 32
    for (int v = 0; v < 4; v++) {
        int u  = v * 256 + tid;
        int n  = u & 63;
        int hh = (u >> 6) & 7;
        int sd = u >> 9;
        const float* hv = hpb + n * 256 + hh * 32;
        const float* av = a_vec + hh * 64 + sd * 32;
        float dot = 0.f;
#pragma unroll
        for (int d = 0; d < 32; d += 4) {
            float4 xv = *(const float4*)&hv[d];
            float4 yv = *(const float4*)&av[d];
            dot += xv.x * yv.x + xv.y * yv.y + xv.z * yv.z + xv.w * yv.w;
        }
        if (sd == 0) lds_es[n * 8 + hh] = dot;
        else         lds_ed[n * 8 + hh] = dot;
    }
    __syncthreads();

    for (int pair = 0; pair < 4; pair++) {
        const int h0 = pair * 2;

        // stage V slice (64 x 64) for this head pair
        for (int v = 0; v < 4; v++) {
            int idx = v * 256 + tid;        // float4 units
            int j   = idx >> 4;
            int c4  = (idx & 15) << 2;
            *(float4*)&lds_V[j * 64 + c4] =
                *(const float4*)&hpb[j * 256 + h0 * 32 + c4];
        }

        // softmax numerators into transposed P tile (threads 0..127)
        if (tid < 128) {
            int i    = tid & 63;
            int hh   = tid >> 6;
            int head = h0 + hh;
            float es = lds_es[i * 8 + head];
            unsigned long long msk = lds_Am[i];
            float m = -1e30f;
            for (int j = 0; j < 64; j++) {
                if ((msk >> j) & 1ULL) {
                    float e = es + lds_ed[j * 8 + head];
                    e = e > 0.f ? e : ALPHA * e;
                    m = fmaxf(m, e);
                }
            }
            float s = 0.f;
            for (int j = 0; j < 64; j++) {
                float p = 0.f;
                if ((msk >> j) & 1ULL) {
                    float e = es + lds_ed[j * 8 + head];
                    e = e > 0.f ? e : ALPHA * e;
                    p = __expf(e - m);
                }
                lds_PT[hh * 4096 + j * 64 + i] = p;
                s += p;
            }
            lds_inv[hh * 64 + i] = (s > 0.f) ? 1.f / s : 0.f;  // isolated rows -> 0
        }
        __syncthreads();

        // out[i, head, d] = inv_s[i] * sum_j P[j,i] * V[j,d]; 4x4 tile/thread
        {
            int hh = tid >> 7;
            int tt = tid & 127;
            int ti = tt & 15, td = tt >> 4;
            int i0 = ti * 4, d0 = td * 4;
            float acc[4][4] = {{0.f}};
            const float* PT = &lds_PT[hh * 4096];
            const float* V  = &lds_V[hh * 32 + d0];
#pragma unroll 4
            for (int j = 0; j < 64; j++) {
                float4 pv = *(const float4*)&PT[j * 64 + i0];
                float4 vv = *(const float4*)&V[j * 64];
                float pr[4] = {pv.x, pv.y, pv.z, pv.w};
                float vr[4] = {vv.x, vv.y, vv.z, vv.w};
#pragma unroll
                for (int a = 0; a < 4; a++)
#pragma unroll
                    for (int c = 0; c < 4; c++)
                        acc[a][c] += pr[a] * vr[c];
            }
            int colbase = pair * 64 + hh * 32 + d0;
#pragma unroll
            for (int a = 0; a < 4; a++) {
                float inv = lds_inv[hh * 64 + i0 + a];
                float* hrow = &hb[(size_t)(i0 + a) * 256 + colbase];
                float4 r = *(const float4*)hrow;
                float o0 = acc[a][0] * inv + r.x;
                float o1 = acc[a][1] * inv + r.y;
                float o2 = acc[a][2] * inv + r.z;
                float o3 = acc[a][3] * inv + r.w;
                float4 res;
                res.x = o0 > 0.f ? o0 : __expf(o0) - 1.f;
                res.y = o1 > 0.f ? o1 : __expf(o1) - 1.f;
                res.z = o2 > 0.f ? o2 : __expf(o2) - 1.f;
                res.w = o3 > 0.f ? o3 : __expf(o3) - 1.f;
                *(float4*)hrow = res;
            }
        }
        __syncthreads();
    }
}

// ---------------------------------------------------------------------------
// Masked mean-pool + 3-layer MLP + elu + 1.5. One block per graph.
// ---------------------------------------------------------------------------
__global__ __launch_bounds__(256)
void pool_mlp(const float* __restrict__ Amat, const float* __restrict__ h,
              const float* __restrict__ W1, const float* __restrict__ b1,
              const float* __restrict__ W2, const float* __restrict__ b2,
              const float* __restrict__ W3, const float* __restrict__ b3,
              float* __restrict__ out)
{
    __shared__ float lds_g[256];
    __shared__ float lds_z1[128];
    __shared__ float lds_z2[128];
    __shared__ unsigned long long lds_m;
    __shared__ float lds_invcnt;

    const int tid = threadIdx.x;
    const int b   = blockIdx.x;
    const float* Ab = Amat + (size_t)b * 4096;
    const float* hb = h    + (size_t)b * 16384;

    if (tid < 64) {
        float dv = Ab[tid * 64 + tid];          // diag == validity
        unsigned long long m = __ballot(dv > 0.f);
        if (tid == 0) { lds_m = m; lds_invcnt = 1.f / (float)__popcll(m); }
    }
    __syncthreads();

    unsigned long long msk = lds_m;
    float invc = lds_invcnt;
    float g = 0.f;
    for (int n = 0; n < 64; n++)
        if ((msk >> n) & 1ULL) g += hb[n * 256 + tid];
    lds_g[tid] = g * invc;
    __syncthreads();

    if (tid < 128) {
        const float* wr = W1 + tid * 256;
        float z = 0.f;
#pragma unroll 8
        for (int k = 0; k < 256; k += 4) {
            float4 wv = *(const float4*)&wr[k];
            z += wv.x * lds_g[k] + wv.y * lds_g[k + 1] + wv.z * lds_g[k + 2] + wv.w * lds_g[k + 3];
        }
        z += b1[tid];
        lds_z1[tid] = z > 0.f ? z : 0.f;
    }
    __syncthreads();

    if (tid < 128) {
        const float* wr = W2 + tid * 128;
        float z = 0.f;
#pragma unroll 8
        for (int k = 0; k < 128; k += 4) {
            float4 wv = *(const float4*)&wr[k];
            z += wv.x * lds_z1[k] + wv.y * lds_z1[k + 1] + wv.z * lds_z1[k + 2] + wv.w * lds_z1[k + 3];
        }
        z += b2[tid];
        lds_z2[tid] = z > 0.f ? z : 0.f;
    }
    __syncthreads();

    if (tid < 64) {
        float p = W3[tid] * lds_z2[tid] + W3[tid + 64] * lds_z2[tid + 64];
        for (int off = 32; off; off >>= 1) p += __shfl_down(p, off);
        if (tid == 0) {
            float z = p + b3[0];
            out[b] = (z > 0.f ? z : __expf(z) - 1.f) + 1.5f;
        }
    }
}

// ---------------------------------------------------------------------------
extern "C" void kernel_launch(void* const* d_in, const int* in_sizes, int n_in,
                              void* d_out, int out_size, void* d_ws, size_t ws_size,
                              hipStream_t stream)
{
    const float* x      = (const float*)d_in[0];
    const float* A      = (const float*)d_in[1];
    const float* W_emb  = (const float*)d_in[2];
    const float* gat_W  = (const float*)d_in[3];
    const float* gat_b  = (const float*)d_in[4];
    const float* gat_a  = (const float*)d_in[5];
    const float* fc_W1  = (const float*)d_in[6];
    const float* fc_b1  = (const float*)d_in[7];
    const float* fc_W2  = (const float*)d_in[8];
    const float* fc_b2  = (const float*)d_in[9];
    const float* fc_W3  = (const float*)d_in[10];
    const float* fc_b3  = (const float*)d_in[11];
    float* out = (float*)d_out;

    // workspace layout (fits in < 204 MB):
    //   h       : 131072*256 f32 = 134217728 B   (residual stream, full batch)
    //   hp      :  65536*256 f32 =  67108864 B   (projection, HALF batch chunk)
    //   weights :  405760 f32    ≈   1.62 MB
    char* ws = (char*)d_ws;
    float* h      = (float*)ws;
    float* hp     = (float*)(ws + 134217728);
    float* wreg   = (float*)(ws + 134217728 + 67108864);
    float* W_embT = wreg;                 // 12544 floats
    float* gat_Wt = wreg + 12544;         // 393216 floats

    transpose_weights<<<1536, 256, 0, stream>>>(W_emb, gat_W, W_embT, gat_Wt);

    // embed: h = x @ W_emb.T   (M=131072, K=49)
    gemm_bt<<<1024, 256, 0, stream>>>(x, FIN, FIN, W_embT, nullptr, h);

    for (int l = 0; l < L_LAYERS; l++) {
        for (int c = 0; c < CHUNKS; c++) {
            const float* h_c = h + (size_t)c * M_CHUNK * D_DIM;
            gemm_bt<<<M_CHUNK / 128, 256, 0, stream>>>(
                h_c, D_DIM, D_DIM,
                gat_Wt + (size_t)l * D_DIM * D_DIM,
                gat_b + l * D_DIM, hp);
            gat_attn<<<G_CHUNK, 256, 0, stream>>>(
                A + (size_t)c * G_CHUNK * 4096, hp,
                gat_a + l * H_HEADS * 2 * DK_DIM,
                h + (size_t)c * M_CHUNK * D_DIM);
        }
    }

    pool_mlp<<<B_GRAPHS, 256, 0, stream>>>(A, h, fc_W1, fc_b1, fc_W2, fc_b2,
                                           fc_W3, fc_b3, out);
}

// Round 3
// 1936.442 us; speedup vs baseline: 1.7190x; 1.7190x over previous
//
#include <hip/hip_runtime.h>
#include <cstdint>
#include <cstddef>

#define B_GRAPHS 2048
#define N_NODES  64
#define FIN      49
#define D_DIM    256
#define H_HEADS  8
#define DK_DIM   32
#define L_LAYERS 6
#define FC_DIM   128
#define ALPHA    0.2f

#define CHUNKS     2
#define G_CHUNK    (B_GRAPHS / CHUNKS)            // 1024 graphs per chunk
#define M_CHUNK    (G_CHUNK * N_NODES)            // 65536 rows per chunk
#define M_FULL     (B_GRAPHS * N_NODES)           // 131072 rows

typedef __bf16 bf16x8 __attribute__((ext_vector_type(8)));
typedef float  f32x4  __attribute__((ext_vector_type(4)));

#define MFMA16(a, b, c) __builtin_amdgcn_mfma_f32_16x16x32_bf16(a, b, c, 0, 0, 0)

// LDS byte offset for (row, 16B-slot) with within-row slot swizzle: keeps
// wave64 ds_read_b128 of 16 rows x 4 slots at the 8-cycle floor (8 lanes per
// 4-bank class, all distinct slots) instead of 16-way conflicts.
__device__ __forceinline__ int swz(int r, int s) {
    return r * 64 + (((s ^ (r & 3)) << 4));
}

// ---------------------------------------------------------------------------
// Weight split: W -> bf16 hi/lo. gat_W is [l][n][k] already (row-major, K-minor)
// W_emb [256][49] padded to [256][64].
// ---------------------------------------------------------------------------
__global__ void convert_weights(const float* __restrict__ W_emb,
                                const float* __restrict__ gat_W,
                                __bf16* __restrict__ Whi_emb,  // [256][64]
                                __bf16* __restrict__ Wlo_emb,
                                __bf16* __restrict__ Whi,      // [6][256][256]
                                __bf16* __restrict__ Wlo)
{
    int idx = blockIdx.x * 256 + threadIdx.x;
    if (idx < 256 * 64) {
        int n = idx >> 6, k = idx & 63;
        float f = (k < FIN) ? W_emb[n * FIN + k] : 0.f;
        __bf16 hi = (__bf16)f;
        Whi_emb[idx] = hi;
        Wlo_emb[idx] = (__bf16)(f - (float)hi);
    }
    if (idx < L_LAYERS * 256 * 256) {
        float f = gat_W[idx];
        __bf16 hi = (__bf16)f;
        Whi[idx] = hi;
        Wlo[idx] = (__bf16)(f - (float)hi);
    }
}

// x [M][49] fp32 -> xhi/xlo [M][64] bf16 (zero-padded)
__global__ void convert_x(const float* __restrict__ x,
                          __bf16* __restrict__ xhi, __bf16* __restrict__ xlo)
{
    int idx = blockIdx.x * 256 + threadIdx.x;   // M*64
    int m = idx >> 6, k = idx & 63;
    float f = (k < FIN) ? x[m * FIN + k] : 0.f;
    __bf16 hi = (__bf16)f;
    xhi[idx] = hi;
    xlo[idx] = (__bf16)(f - (float)hi);
}

// ---------------------------------------------------------------------------
// C[M,256] = A[M,K] @ B^T + bias via 3-term bf16-split MFMA (fp32-accurate).
// B given as [256 n][K k] bf16 hi/lo. BM=128, BN=128, BK=32, 256 thr (2x2 waves).
// A either fp32 (split in-kernel during staging) or pre-split bf16 hi/lo.
// Double-buffered LDS, 1 barrier per k-step, reg-prefetch of next tile.
// ---------------------------------------------------------------------------
template<bool A_BF16>
__global__ __launch_bounds__(256, 2)
void gemm_mfma(const float* __restrict__ Af32,
               const __bf16* __restrict__ Ahi, const __bf16* __restrict__ Alo,
               int K,
               const __bf16* __restrict__ Bhi, const __bf16* __restrict__ Blo,
               const float* __restrict__ bias,
               float* __restrict__ C)
{
    // per buffer: Ahi@0 (8K), Alo@8192, Bhi@16384, Blo@24576  => 32KB
    __shared__ __align__(16) char lds[2][32768];

    const int tid  = threadIdx.x;
    const int m0   = blockIdx.x * 128;
    const int n0   = blockIdx.y * 128;
    const int lane = tid & 63;
    const int wid  = tid >> 6;
    const int wr   = wid >> 1, wc = wid & 1;
    const int KSTEPS = K >> 5;

    float4 regA[2][2];
    bf16x8 regAh[2], regAl[2];
    bf16x8 regBh[2], regBl[2];

    f32x4 acc[4][4];
#pragma unroll
    for (int i = 0; i < 4; i++)
#pragma unroll
        for (int j = 0; j < 4; j++) acc[i][j] = (f32x4){0.f, 0.f, 0.f, 0.f};

    auto load_stage = [&](int k0) {
#pragma unroll
        for (int g = 0; g < 2; g++) {
            int u = g * 256 + tid, r = u >> 2, s = u & 3;
            if (A_BF16) {
                regAh[g] = *(const bf16x8*)(Ahi + (size_t)(m0 + r) * K + k0 + s * 8);
                regAl[g] = *(const bf16x8*)(Alo + (size_t)(m0 + r) * K + k0 + s * 8);
            } else {
                const float* ap = Af32 + (size_t)(m0 + r) * K + k0 + s * 8;
                regA[g][0] = *(const float4*)ap;
                regA[g][1] = *(const float4*)(ap + 4);
            }
            regBh[g] = *(const bf16x8*)(Bhi + (size_t)(n0 + r) * K + k0 + s * 8);
            regBl[g] = *(const bf16x8*)(Blo + (size_t)(n0 + r) * K + k0 + s * 8);
        }
    };

    auto write_stage = [&](int buf) {
        char* base = lds[buf];
#pragma unroll
        for (int g = 0; g < 2; g++) {
            int u = g * 256 + tid, r = u >> 2, s = u & 3;
            int off = swz(r, s);
            bf16x8 h8, l8;
            if (A_BF16) {
                h8 = regAh[g];
                l8 = regAl[g];
            } else {
                float fv[8] = {regA[g][0].x, regA[g][0].y, regA[g][0].z, regA[g][0].w,
                               regA[g][1].x, regA[g][1].y, regA[g][1].z, regA[g][1].w};
#pragma unroll
                for (int j = 0; j < 8; j++) {
                    __bf16 hi = (__bf16)fv[j];
                    h8[j] = hi;
                    l8[j] = (__bf16)(fv[j] - (float)hi);
                }
            }
            *(bf16x8*)(base + off)         = h8;
            *(bf16x8*)(base + 8192 + off)  = l8;
            *(bf16x8*)(base + 16384 + off) = regBh[g];
            *(bf16x8*)(base + 24576 + off) = regBl[g];
        }
    };

    auto compute = [&](int buf) {
        const char* base = lds[buf];
        const int s = lane >> 4;
        bf16x8 ah[4], al[4];
#pragma unroll
        for (int mf = 0; mf < 4; mf++) {
            int r = wr * 64 + mf * 16 + (lane & 15);
            int off = swz(r, s);
            ah[mf] = *(const bf16x8*)(base + off);
            al[mf] = *(const bf16x8*)(base + 8192 + off);
        }
#pragma unroll
        for (int nf = 0; nf < 4; nf++) {
            int r = wc * 64 + nf * 16 + (lane & 15);
            int off = swz(r, s);
            bf16x8 bh = *(const bf16x8*)(base + 16384 + off);
            bf16x8 bl = *(const bf16x8*)(base + 24576 + off);
#pragma unroll
            for (int mf = 0; mf < 4; mf++) {
                acc[mf][nf] = MFMA16(ah[mf], bh, acc[mf][nf]);
                acc[mf][nf] = MFMA16(ah[mf], bl, acc[mf][nf]);
                acc[mf][nf] = MFMA16(al[mf], bh, acc[mf][nf]);
            }
        }
    };

    load_stage(0);
    write_stage(0);
    if (KSTEPS > 1) load_stage(32);
    __syncthreads();

    for (int ks = 0; ks < KSTEPS; ks++) {
        compute(ks & 1);
        if (ks + 1 < KSTEPS) {
            write_stage((ks + 1) & 1);
            if (ks + 2 < KSTEPS) load_stage((ks + 2) << 5);
        }
        __syncthreads();
    }

    // epilogue: D row=(lane>>4)*4+reg, col=lane&15 (verified 16x16x32 bf16 C/D map)
#pragma unroll
    for (int nf = 0; nf < 4; nf++) {
        int col = n0 + wc * 64 + nf * 16 + (lane & 15);
        float bv = bias ? bias[col] : 0.f;
#pragma unroll
        for (int mf = 0; mf < 4; mf++) {
            int rbase = m0 + wr * 64 + mf * 16 + (lane >> 4) * 4;
#pragma unroll
            for (int rr = 0; rr < 4; rr++)
                C[(size_t)(rbase + rr) * 256 + col] = acc[mf][nf][rr] + bv;
        }
    }
}

// ---------------------------------------------------------------------------
// Fused GAT attention for one layer. One block per graph, 256 threads.
// max-pass eliminated: leaky_relu is monotonic, so
// max_j in mask leaky(es_i+ed_j) <= leaky(es_i + max_all_j ed_j) = m_hat;
// exp(e - m_hat) <= 1, ratios unchanged.
// ---------------------------------------------------------------------------
__global__ __launch_bounds__(256, 2)
void gat_attn(const float* __restrict__ Amat,
              const float* __restrict__ hp,
              const float* __restrict__ a_vec,   // [8][64] for this layer
              float* __restrict__ h)
{
    __shared__ float lds_PT[2 * 64 * 64];
    __shared__ float lds_V[64 * 64];
    __shared__ float lds_es[64 * 8];
    __shared__ float lds_ed[64 * 8];
    __shared__ float lds_inv[2 * 64];
    __shared__ float lds_edmax[8];
    __shared__ unsigned long long lds_Am[64];

    const int tid  = threadIdx.x;
    const int b    = blockIdx.x;
    const int lane = tid & 63;
    const int w    = tid >> 6;

    const float* Ab  = Amat + (size_t)b * 4096;
    const float* hpb = hp   + (size_t)b * 64 * 256;
    float*       hb  = h    + (size_t)b * 64 * 256;

    // A row bitmasks via wave ballot
    for (int v = 0; v < 16; v++) {
        float a = Ab[v * 256 + tid];
        unsigned long long m = __ballot(a > 0.f);
        if (lane == 0) lds_Am[v * 4 + w] = m;
    }

    // e_src / e_dst : 1024 dot-products of length 32
    for (int v = 0; v < 4; v++) {
        int u  = v * 256 + tid;
        int n  = u & 63;
        int hh = (u >> 6) & 7;
        int sd = u >> 9;
        const float* hv = hpb + n * 256 + hh * 32;
        const float* av = a_vec + hh * 64 + sd * 32;
        float dot = 0.f;
#pragma unroll
        for (int d = 0; d < 32; d += 4) {
            float4 xv = *(const float4*)&hv[d];
            float4 yv = *(const float4*)&av[d];
            dot += xv.x * yv.x + xv.y * yv.y + xv.z * yv.z + xv.w * yv.w;
        }
        if (sd == 0) lds_es[n * 8 + hh] = dot;
        else         lds_ed[n * 8 + hh] = dot;
    }
    __syncthreads();

    // per-head global max of ed (upper bound for softmax stabilization)
    for (int hh = w; hh < 8; hh += 4) {
        float v = lds_ed[lane * 8 + hh];
        for (int off = 32; off; off >>= 1) v = fmaxf(v, __shfl_xor(v, off));
        if (lane == 0) lds_edmax[hh] = v;
    }
    __syncthreads();

    for (int pair = 0; pair < 4; pair++) {
        const int h0 = pair * 2;

        // stage V slice (64 x 64) for this head pair
        for (int v = 0; v < 4; v++) {
            int idx = v * 256 + tid;
            int j   = idx >> 4;
            int c4  = (idx & 15) << 2;
            *(float4*)&lds_V[j * 64 + c4] =
                *(const float4*)&hpb[j * 256 + h0 * 32 + c4];
        }

        // softmax numerators (single pass, m_hat bound), threads 0..127
        if (tid < 128) {
            int i    = tid & 63;
            int hh   = tid >> 6;
            int head = h0 + hh;
            float es = lds_es[i * 8 + head];
            unsigned long long msk = lds_Am[i];
            float mh = es + lds_edmax[head];
            mh = mh > 0.f ? mh : ALPHA * mh;
            float s = 0.f;
            for (int j = 0; j < 64; j++) {
                float p = 0.f;
                if ((msk >> j) & 1ULL) {
                    float e = es + lds_ed[j * 8 + head];
                    e = e > 0.f ? e : ALPHA * e;
                    p = __expf(e - mh);
                }
                lds_PT[hh * 4096 + j * 64 + i] = p;
                s += p;
            }
            lds_inv[hh * 64 + i] = (s > 0.f) ? 1.f / s : 0.f;
        }
        __syncthreads();

        // out[i, head, d] = inv_s[i] * sum_j P[j,i] * V[j,d]; 4x4 tile/thread
        {
            int hh = tid >> 7;
            int tt = tid & 127;
            int ti = tt & 15, td = tt >> 4;
            int i0 = ti * 4, d0 = td * 4;
            float acc[4][4] = {{0.f}};
            const float* PT = &lds_PT[hh * 4096];
            const float* V  = &lds_V[hh * 32 + d0];
#pragma unroll 4
            for (int j = 0; j < 64; j++) {
                float4 pv = *(const float4*)&PT[j * 64 + i0];
                float4 vv = *(const float4*)&V[j * 64];
                float pr[4] = {pv.x, pv.y, pv.z, pv.w};
                float vr[4] = {vv.x, vv.y, vv.z, vv.w};
#pragma unroll
                for (int a = 0; a < 4; a++)
#pragma unroll
                    for (int c = 0; c < 4; c++)
                        acc[a][c] += pr[a] * vr[c];
            }
            int colbase = pair * 64 + hh * 32 + d0;
#pragma unroll
            for (int a = 0; a < 4; a++) {
                float inv = lds_inv[hh * 64 + i0 + a];
                float* hrow = &hb[(size_t)(i0 + a) * 256 + colbase];
                float4 r = *(const float4*)hrow;
                float o0 = acc[a][0] * inv + r.x;
                float o1 = acc[a][1] * inv + r.y;
                float o2 = acc[a][2] * inv + r.z;
                float o3 = acc[a][3] * inv + r.w;
                float4 res;
                res.x = o0 > 0.f ? o0 : __expf(o0) - 1.f;
                res.y = o1 > 0.f ? o1 : __expf(o1) - 1.f;
                res.z = o2 > 0.f ? o2 : __expf(o2) - 1.f;
                res.w = o3 > 0.f ? o3 : __expf(o3) - 1.f;
                *(float4*)hrow = res;
            }
        }
        __syncthreads();
    }
}

// ---------------------------------------------------------------------------
// Masked mean-pool + 3-layer MLP + elu + 1.5. One block per graph.
// ---------------------------------------------------------------------------
__global__ __launch_bounds__(256)
void pool_mlp(const float* __restrict__ Amat, const float* __restrict__ h,
              const float* __restrict__ W1, const float* __restrict__ b1,
              const float* __restrict__ W2, const float* __restrict__ b2,
              const float* __restrict__ W3, const float* __restrict__ b3,
              float* __restrict__ out)
{
    __shared__ float lds_g[256];
    __shared__ float lds_z1[128];
    __shared__ float lds_z2[128];
    __shared__ unsigned long long lds_m;
    __shared__ float lds_invcnt;

    const int tid = threadIdx.x;
    const int b   = blockIdx.x;
    const float* Ab = Amat + (size_t)b * 4096;
    const float* hb = h    + (size_t)b * 16384;

    if (tid < 64) {
        float dv = Ab[tid * 64 + tid];
        unsigned long long m = __ballot(dv > 0.f);
        if (tid == 0) { lds_m = m; lds_invcnt = 1.f / (float)__popcll(m); }
    }
    __syncthreads();

    unsigned long long msk = lds_m;
    float invc = lds_invcnt;
    float g = 0.f;
    for (int n = 0; n < 64; n++)
        if ((msk >> n) & 1ULL) g += hb[n * 256 + tid];
    lds_g[tid] = g * invc;
    __syncthreads();

    if (tid < 128) {
        const float* wr = W1 + tid * 256;
        float z = 0.f;
#pragma unroll 8
        for (int k = 0; k < 256; k += 4) {
            float4 wv = *(const float4*)&wr[k];
            z += wv.x * lds_g[k] + wv.y * lds_g[k + 1] + wv.z * lds_g[k + 2] + wv.w * lds_g[k + 3];
        }
        z += b1[tid];
        lds_z1[tid] = z > 0.f ? z : 0.f;
    }
    __syncthreads();

    if (tid < 128) {
        const float* wr = W2 + tid * 128;
        float z = 0.f;
#pragma unroll 8
        for (int k = 0; k < 128; k += 4) {
            float4 wv = *(const float4*)&wr[k];
            z += wv.x * lds_z1[k] + wv.y * lds_z1[k + 1] + wv.z * lds_z1[k + 2] + wv.w * lds_z1[k + 3];
        }
        z += b2[tid];
        lds_z2[tid] = z > 0.f ? z : 0.f;
    }
    __syncthreads();

    if (tid < 64) {
        float p = W3[tid] * lds_z2[tid] + W3[tid + 64] * lds_z2[tid + 64];
        for (int off = 32; off; off >>= 1) p += __shfl_down(p, off);
        if (tid == 0) {
            float z = p + b3[0];
            out[b] = (z > 0.f ? z : __expf(z) - 1.f) + 1.5f;
        }
    }
}

// ---------------------------------------------------------------------------
extern "C" void kernel_launch(void* const* d_in, const int* in_sizes, int n_in,
                              void* d_out, int out_size, void* d_ws, size_t ws_size,
                              hipStream_t stream)
{
    const float* x      = (const float*)d_in[0];
    const float* A      = (const float*)d_in[1];
    const float* W_emb  = (const float*)d_in[2];
    const float* gat_W  = (const float*)d_in[3];
    const float* gat_b  = (const float*)d_in[4];
    const float* gat_a  = (const float*)d_in[5];
    const float* fc_W1  = (const float*)d_in[6];
    const float* fc_b1  = (const float*)d_in[7];
    const float* fc_W2  = (const float*)d_in[8];
    const float* fc_b2  = (const float*)d_in[9];
    const float* fc_W3  = (const float*)d_in[10];
    const float* fc_b3  = (const float*)d_in[11];
    float* out = (float*)d_out;

    // workspace layout (~203.5 MB):
    //   h  fp32 [131072][256]                       @ 0          134217728 B
    //   hp fp32 [65536][256] (chunk)                @ 134217728   67108864 B
    //     (xhi/xlo [131072][64] bf16, 33.5 MB, alias hp before the layer loop)
    //   Whi_emb/Wlo_emb [256][64] bf16              @ 201326592   2x32768 B
    //   Whi/Wlo [6][256][256] bf16                  @ 201392128   2x786432 B
    char* ws = (char*)d_ws;
    float*  h       = (float*)ws;
    float*  hp      = (float*)(ws + 134217728);
    __bf16* xhi     = (__bf16*)(ws + 134217728);
    __bf16* xlo     = (__bf16*)(ws + 134217728 + 16777216);
    __bf16* Whi_emb = (__bf16*)(ws + 201326592);
    __bf16* Wlo_emb = (__bf16*)(ws + 201326592 + 32768);
    __bf16* Whi     = (__bf16*)(ws + 201392128);
    __bf16* Wlo     = (__bf16*)(ws + 201392128 + 786432);

    convert_weights<<<1536, 256, 0, stream>>>(W_emb, gat_W, Whi_emb, Wlo_emb, Whi, Wlo);
    convert_x<<<M_FULL * 64 / 256, 256, 0, stream>>>(x, xhi, xlo);

    // embed: h = x @ W_emb.T   (M=131072, K=64 padded, bf16-split A)
    gemm_mfma<true><<<dim3(M_FULL / 128, 2), 256, 0, stream>>>(
        nullptr, xhi, xlo, 64, Whi_emb, Wlo_emb, nullptr, h);

    for (int l = 0; l < L_LAYERS; l++) {
        for (int c = 0; c < CHUNKS; c++) {
            float* h_c = h + (size_t)c * M_CHUNK * D_DIM;
            gemm_mfma<false><<<dim3(M_CHUNK / 128, 2), 256, 0, stream>>>(
                h_c, nullptr, nullptr, 256,
                Whi + (size_t)l * 65536, Wlo + (size_t)l * 65536,
                gat_b + l * D_DIM, hp);
            gat_attn<<<G_CHUNK, 256, 0, stream>>>(
                A + (size_t)c * G_CHUNK * 4096, hp,
                gat_a + l * H_HEADS * 2 * DK_DIM, h_c);
        }
    }

    pool_mlp<<<B_GRAPHS, 256, 0, stream>>>(A, h, fc_W1, fc_b1, fc_W2, fc_b2,
                                           fc_W3, fc_b3, out);
}